// Round 16
// baseline (216.543 us; speedup 1.0000x reference)
//
#include <hip/hip_runtime.h>
#include <math.h>

// Problem constants
#define T_TOKENS 32768
#define DIM      2048
#define NEXP     256
#define NGROUP   8
#define GSIZE    32
#define TOPG     4
#define TOPK     8
#define SCALE    2.5
#define TAU      1e-5f     // rescue margin; >=25x RMS of 3-term bf16-split err

// Main-pass tiling
#define BM  64
#define NIT 16             // iterations of 128-k (4 sub-steps of 32)
#define SC_STRIDE 257

#define RLIST_OFF 16                 // ints; ws[0] = counter
#define WPACK_OFF_BYTES (1 << 18)    // 256 KiB into d_ws

typedef __attribute__((ext_vector_type(8))) short bf16x8;
typedef __attribute__((ext_vector_type(8))) unsigned short u16x8;
typedef __attribute__((ext_vector_type(4))) float f32x4;

__device__ __forceinline__ unsigned short f2bf_rne(float f) {
    unsigned u = __float_as_uint(f);
    u += 0x7fffu + ((u >> 16) & 1u);
    return (unsigned short)(u >> 16);
}
__device__ __forceinline__ float bf2f(unsigned short h) {
    return __uint_as_float(((unsigned)h) << 16);
}

// LDS-only barrier: orders ds ops across the workgroup but leaves global
// (vmcnt) loads in flight.
__device__ __forceinline__ void lds_barrier() {
    __builtin_amdgcn_sched_barrier(0);
    asm volatile("s_waitcnt lgkmcnt(0)" ::: "memory");
    __builtin_amdgcn_s_barrier();
    __builtin_amdgcn_sched_barrier(0);
}

// ------------------------------------------------------------- pack W ----
// Wpack slot (s, n, h, lane) holds 8 bf16: W[e=16n+(lane&15)][k=32s+(lane>>4)*8+i]
__global__ void pack_w_kernel(const float* __restrict__ Wt,
                              unsigned short* __restrict__ wp,
                              int* __restrict__ ws) {
    if (blockIdx.x == 0 && threadIdx.x == 0) ws[0] = 0;   // rescue counter
    const int slot = blockIdx.x * 256 + threadIdx.x;      // 0..65535
    const int lane = slot & 63;
    const int n    = (slot >> 6) & 15;
    const int s    = slot >> 10;
    const int e    = n * 16 + (lane & 15);
    const int k0   = s * 32 + (lane >> 4) * 8;
    const float* src = Wt + (size_t)e * DIM + k0;
    const float4 v0 = *(const float4*)src;
    const float4 v1 = *(const float4*)(src + 4);
    const float a[8] = {v0.x, v0.y, v0.z, v0.w, v1.x, v1.y, v1.z, v1.w};
    union { unsigned short u[8]; u16x8 v; } uh, ul;
    #pragma unroll
    for (int i = 0; i < 8; ++i) {
        const unsigned short hb = f2bf_rne(a[i]);
        uh.u[i] = hb;
        ul.u[i] = f2bf_rne(a[i] - bf2f(hb));
    }
    const size_t base = ((size_t)(s * 16 + n) * 2) * 64 + lane;
    *(u16x8*)(wp + base * 8)        = uh.v;   // hi
    *(u16x8*)(wp + (base + 64) * 8) = ul.v;   // lo
}

// ---------------------------------------------------------------- main ----
// r15 structure with BK=128: 4 sub-steps of 32-k per barrier period, 16
// periods (was 32). A dbuf = 2 x 32 KiB, still unioned under Sc -> LDS
// footprint and occupancy unchanged (2 blocks/CU, 16 waves).
__global__ __launch_bounds__(512, 4) void router_main(
    const float* __restrict__ H,
    const float* __restrict__ bias,
    const unsigned short* __restrict__ wp,
    float* __restrict__ out,
    int* __restrict__ ws)
{
    __shared__ __align__(16) char smraw[BM * SC_STRIDE * 4];   // 65792 B
    __shared__ float biasS[NEXP];

    typedef unsigned short AhlBuf[4][2][4][64][8];   // [sub][h][m][slot][i] = 32 KiB
    AhlBuf* Ahl = reinterpret_cast<AhlBuf*>(smraw);  // Ahl[buf], 2 bufs = 64 KiB
    float*  Sc  = reinterpret_cast<float*>(smraw);

    const int tid  = threadIdx.x;
    const int lane = tid & 63;
    const int w    = tid >> 6;           // wave 0..7
    const int t0   = blockIdx.x * BM;

    if (tid < NEXP) biasS[tid] = bias[tid];

    f32x4 acc[4][2];   // [m][jj], expert tile = 2w+jj
    #pragma unroll
    for (int m = 0; m < 4; ++m)
        #pragma unroll
        for (int jj = 0; jj < 2; ++jj)
            acc[m][jj] = (f32x4){0.f, 0.f, 0.f, 0.f};

    // A staging: 512 threads x 128-k iter; thread covers row=tid>>3, two
    // k-octets: koct*8 (subs 0/1) and 64+koct*8 (subs 2/3).
    const int arow = tid >> 3;           // 0..63
    const int koct = tid & 7;            // 0..7
    const int slo  = koct >> 2;          // sub for k-lo half (0/1)
    const int kq   = koct & 3;
    const int am   = arow >> 4;
    // bank-quad XOR swizzle (r15-verified); sub&1 == koct>>2 for both halves
    const int lw   = (kq << 4) | (((arow & 15) ^ (kq << 1) ^ slo) & 15);
    const float* Aptr = H + (size_t)(t0 + arow) * DIM + koct * 8;

    auto loadH = [&](int it, float4 (&x)[4]) {
        const float* p = Aptr + (size_t)it * 128;
        x[0] = *(const float4*)p;
        x[1] = *(const float4*)(p + 4);
        x[2] = *(const float4*)(p + 64);
        x[3] = *(const float4*)(p + 68);
    };
    auto cvtWrite = [&](int b, int sb, const float4& x0, const float4& x1) {
        const float a[8] = {x0.x, x0.y, x0.z, x0.w, x1.x, x1.y, x1.z, x1.w};
        union { unsigned short u[8]; u16x8 v; } uh, ul;
        #pragma unroll
        for (int i = 0; i < 8; ++i) {
            const unsigned short hb = f2bf_rne(a[i]);
            uh.u[i] = hb;
            ul.u[i] = f2bf_rne(a[i] - bf2f(hb));
        }
        *(u16x8*)&Ahl[b][sb][0][am][lw][0] = uh.v;
        *(u16x8*)&Ahl[b][sb][1][am][lw][0] = ul.v;
    };
    auto stageIter = [&](int b, const float4 (&x)[4]) {
        cvtWrite(b, slo,     x[0], x[1]);   // k-lo -> subs 0/1
        cvtWrite(b, 2 + slo, x[2], x[3]);   // k-hi -> subs 2/3
    };
    auto loadB = [&](int s, bf16x8 (&Bh)[2], bf16x8 (&Bl)[2]) {
        #pragma unroll
        for (int jj = 0; jj < 2; ++jj) {
            const size_t slot = ((size_t)(s * 16 + 2 * w + jj) * 2) * 64 + lane;
            Bh[jj] = *(const bf16x8*)(wp + slot * 8);
            Bl[jj] = *(const bf16x8*)(wp + (slot + 64) * 8);
        }
    };
    auto computeSub = [&](int b, int ss, bf16x8 (&Bh)[2], bf16x8 (&Bl)[2]) {
        // inverse swizzle; ss compile-time per call site
        const int rslot = (lane & 48) | (((lane & 15) ^ ((lane >> 4) << 1) ^ (ss & 1)) & 15);
        bf16x8 Ah[4], Al[4];
        #pragma unroll
        for (int m = 0; m < 4; ++m) {
            Ah[m] = *(const bf16x8*)&Ahl[b][ss][0][m][rslot][0];
            Al[m] = *(const bf16x8*)&Ahl[b][ss][1][m][rslot][0];
        }
        __builtin_amdgcn_s_setprio(1);
        #pragma unroll
        for (int m = 0; m < 4; ++m)
            #pragma unroll
            for (int jj = 0; jj < 2; ++jj) {
                acc[m][jj] = __builtin_amdgcn_mfma_f32_16x16x32_bf16(Al[m], Bh[jj], acc[m][jj], 0, 0, 0);
                acc[m][jj] = __builtin_amdgcn_mfma_f32_16x16x32_bf16(Ah[m], Bl[jj], acc[m][jj], 0, 0, 0);
                acc[m][jj] = __builtin_amdgcn_mfma_f32_16x16x32_bf16(Ah[m], Bh[jj], acc[m][jj], 0, 0, 0);
            }
        __builtin_amdgcn_s_setprio(0);
    };

    bf16x8 Ba_h[2], Ba_l[2], Bb_h[2], Bb_l[2];
    float4 hS[4], hL[4];

    // prologue: stage iter 0 into buf0; prefetch h(1); B sub 0
    {
        float4 c[4];
        loadH(0, c);
        stageIter(0, c);
    }
    loadH(1, hS);
    loadB(0, Ba_h, Ba_l);
    lds_barrier();

    for (int it = 0; it < NIT; it += 2) {
        // ---- iter it: compute buf0 subs 4it..4it+3; stage buf1 = A(it+1) ----
        {
            const int s0 = 4 * it;
            loadH(min(it + 2, NIT - 1), hL);
            stageIter(1, hS);
            loadB(s0 + 1, Bb_h, Bb_l);
            computeSub(0, 0, Ba_h, Ba_l);
            loadB(s0 + 2, Ba_h, Ba_l);
            computeSub(0, 1, Bb_h, Bb_l);
            loadB(s0 + 3, Bb_h, Bb_l);
            computeSub(0, 2, Ba_h, Ba_l);
            loadB(min(s0 + 4, 4 * NIT - 1), Ba_h, Ba_l);
            computeSub(0, 3, Bb_h, Bb_l);
            lds_barrier();
        }
        // ---- iter it+1: compute buf1 subs 4it+4..4it+7; stage buf0 ----
        {
            const int s0 = 4 * (it + 1);
            loadH(min(it + 3, NIT - 1), hS);
            if (it + 2 < NIT) stageIter(0, hL);
            loadB(s0 + 1, Bb_h, Bb_l);
            computeSub(1, 0, Ba_h, Ba_l);
            loadB(s0 + 2, Ba_h, Ba_l);
            computeSub(1, 1, Bb_h, Bb_l);
            loadB(s0 + 3, Bb_h, Bb_l);
            computeSub(1, 2, Ba_h, Ba_l);
            loadB(min(s0 + 4, 4 * NIT - 1), Ba_h, Ba_l);
            computeSub(1, 3, Bb_h, Bb_l);
            lds_barrier();
        }
    }

    // ---- epilogue: biased sigmoid -> Sc ----
    const int rbase = (lane >> 4) * 4;
    const int cc    = lane & 15;
    #pragma unroll
    for (int m = 0; m < 4; ++m)
        #pragma unroll
        for (int jj = 0; jj < 2; ++jj)
            #pragma unroll
            for (int r = 0; r < 4; ++r) {
                const int token  = 16 * m + rbase + r;
                const int expert = 16 * (2 * w + jj) + cc;
                const float sg = 1.0f / (1.0f + expf(-acc[m][jj][r]));
                Sc[token * SC_STRIDE + expert] = sg + biasS[expert];
            }
    __syncthreads();

    // ---- routing (fp32) + margin check (round-4..15 proven) ----
    if (tid < BM) {
        float* row = &Sc[tid * SC_STRIDE];

        float gs[NGROUP];
        for (int g = 0; g < NGROUP; ++g) {
            const int base = g * GSIZE;
            float m1 = -3e38f, m2 = -3e38f;
            for (int j = 0; j < GSIZE; ++j) {
                const float v = row[base + j];
                if (v > m1) { m2 = m1; m1 = v; }
                else if (v > m2) { m2 = v; }
            }
            gs[g] = m1 + m2;
        }

        unsigned gsel = 0;
        float minSel = 3e38f, maxUn = -3e38f;
        #pragma unroll
        for (int g = 0; g < NGROUP; ++g) {
            int rank = 0;
            #pragma unroll
            for (int h = 0; h < NGROUP; ++h)
                rank += (gs[h] > gs[g]) || (gs[h] == gs[g] && h < g);
            if (rank < TOPG) { gsel |= 1u << g; minSel = fminf(minSel, gs[g]); }
            else             { maxUn = fmaxf(maxUn, gs[g]); }
        }
        float minMargin = minSel - maxUn;

        float wk[TOPK];
        int   ik[TOPK];
        float wsum = 0.0f;
        float prev = 3e38f;
        #pragma unroll
        for (int k = 0; k < TOPK + 1; ++k) {
            float bv = -3e38f;
            int   bi = 0;
            for (int g = 0; g < NGROUP; ++g) {
                if (!((gsel >> g) & 1u)) continue;
                const int base = g * GSIZE;
                for (int j = 0; j < GSIZE; ++j) {
                    const int e = base + j;
                    const float v = row[e];
                    if (v > bv) { bv = v; bi = e; }
                }
            }
            if (k > 0) minMargin = fminf(minMargin, prev - bv);
            prev = bv;
            if (k < TOPK) {
                const float wv = bv - biasS[bi];
                wk[k] = wv; ik[k] = bi; wsum += wv;
                row[bi] = -3e38f;
            }
        }

        const float norm = (float)SCALE / wsum;
        const size_t t = (size_t)(t0 + tid);
        float* oi = out + t * TOPK;
        float* ow = out + (size_t)T_TOKENS * TOPK + t * TOPK;
        #pragma unroll
        for (int k = 0; k < TOPK; ++k) {
            oi[k] = (float)ik[k];
            ow[k] = wk[k] * norm;
        }

        if (minMargin < TAU) {
            const int r = atomicAdd(ws, 1);
            ws[RLIST_OFF + r] = t0 + tid;
        }
    }
}

// -------------------------------------------------------------- rescue ----
// 1 token per block-iteration; 512 threads = 256 experts x 2 k-halves for the
// fp64 dot; routing is wave-parallel (r3-verified shfl logic).
__global__ __launch_bounds__(512) void router_rescue(
    const float* __restrict__ H,
    const float* __restrict__ Wt,
    const float* __restrict__ bias,
    float* __restrict__ out,
    const int* __restrict__ ws)
{
    __shared__ float  Hrow[DIM];        // 8 KiB
    __shared__ double PartD[2][NEXP];   // 4 KiB
    __shared__ double Sd[NEXP];         // 2 KiB
    __shared__ double biasD[NEXP];      // 2 KiB

    const int tid = threadIdx.x;
    const int nR  = ws[0];
    const int re  = tid & 255;          // expert
    const int kh  = tid >> 8;           // k-half 0/1

    if (tid < NEXP) biasD[tid] = (double)bias[tid];

    for (int idx = blockIdx.x; idx < nR; idx += gridDim.x) {
        const size_t t = (size_t)ws[RLIST_OFF + idx];
        __syncthreads();

        *(float4*)&Hrow[tid * 4] = *(const float4*)&H[t * DIM + tid * 4];
        __syncthreads();

        {
            const float* wr = Wt + (size_t)re * DIM + kh * 1024;
            const float* hr = Hrow + kh * 1024;
            double c0 = 0.0, c1 = 0.0, c2 = 0.0, c3 = 0.0;
            #pragma unroll 4
            for (int k = 0; k < 1024; k += 4) {
                const float4 wv = *(const float4*)(wr + k);
                c0 = fma((double)hr[k + 0], (double)wv.x, c0);
                c1 = fma((double)hr[k + 1], (double)wv.y, c1);
                c2 = fma((double)hr[k + 2], (double)wv.z, c2);
                c3 = fma((double)hr[k + 3], (double)wv.w, c3);
            }
            PartD[kh][re] = ((c0 + c1) + c2) + c3;
        }
        __syncthreads();

        if (tid < NEXP) {
            const double sum = PartD[0][tid] + PartD[1][tid];
            Sd[tid] = 1.0 / (1.0 + exp(-sum)) + biasD[tid];
        }
        __syncthreads();

        if (tid < 64) {
            const int lane = tid;
            const int e0   = lane * 4;
            const int gm   = lane >> 3;

            double sv[4];
            #pragma unroll
            for (int j = 0; j < 4; ++j) sv[j] = Sd[e0 + j];

            double m1 = sv[0], m2 = -1e300;
            #pragma unroll
            for (int j = 1; j < 4; ++j) {
                if (sv[j] > m1) { m2 = m1; m1 = sv[j]; }
                else if (sv[j] > m2) { m2 = sv[j]; }
            }
            #pragma unroll
            for (int mask = 1; mask <= 4; mask <<= 1) {
                const double o1 = __shfl_xor(m1, mask);
                const double o2 = __shfl_xor(m2, mask);
                const double lo = fmin(m1, o1);
                m1 = fmax(m1, o1);
                m2 = fmax(lo, fmax(m2, o2));
            }
            const double gsm = m1 + m2;

            double gsd[NGROUP];
            #pragma unroll
            for (int g = 0; g < NGROUP; ++g) gsd[g] = __shfl(gsm, g * 8);

            unsigned gsel = 0;
            #pragma unroll
            for (int g = 0; g < NGROUP; ++g) {
                int rank = 0;
                #pragma unroll
                for (int h = 0; h < NGROUP; ++h)
                    rank += (gsd[h] > gsd[g]) || (gsd[h] == gsd[g] && h < g);
                if (rank < TOPG) gsel |= 1u << g;
            }
            const bool allowed = (gsel >> gm) & 1u;

            double wkd[TOPK];
            int    ikd[TOPK];
            double wsum = 0.0;
            #pragma unroll
            for (int k = 0; k < TOPK; ++k) {
                double bv = -1e300;
                int    be = 1 << 30;
                if (allowed) {
                    #pragma unroll
                    for (int j = 0; j < 4; ++j)
                        if (sv[j] > bv) { bv = sv[j]; be = e0 + j; }
                }
                #pragma unroll
                for (int mask = 1; mask <= 32; mask <<= 1) {
                    const double ov = __shfl_xor(bv, mask);
                    const int    oe = __shfl_xor(be, mask);
                    if (ov > bv || (ov == bv && oe < be)) { bv = ov; be = oe; }
                }
                const double wv = bv - biasD[be];
                wkd[k] = wv; ikd[k] = be; wsum += wv;
                const bool own = ((be >> 2) == lane);
                #pragma unroll
                for (int j = 0; j < 4; ++j)
                    if (own && (be & 3) == j) sv[j] = -1e300;
            }

            if (lane == 0) {
                const double norm = SCALE / wsum;
                float* oi = out + t * TOPK;
                float* ow = out + (size_t)T_TOKENS * TOPK + t * TOPK;
                #pragma unroll
                for (int k = 0; k < TOPK; ++k) {
                    oi[k] = (float)ikd[k];
                    ow[k] = (float)(wkd[k] * norm);
                }
            }
        }
    }
}

extern "C" void kernel_launch(void* const* d_in, const int* in_sizes, int n_in,
                              void* d_out, int out_size, void* d_ws, size_t ws_size,
                              hipStream_t stream) {
    const float* H    = (const float*)d_in[0];
    const float* Wt   = (const float*)d_in[1];
    const float* bias = (const float*)d_in[2];
    float* out = (float*)d_out;
    int*   ws  = (int*)d_ws;
    unsigned short* wp = (unsigned short*)((char*)d_ws + WPACK_OFF_BYTES);

    pack_w_kernel<<<256, 256, 0, stream>>>(Wt, wp, ws);
    router_main<<<T_TOKENS / BM, 512, 0, stream>>>(H, bias, wp, out, ws);
    router_rescue<<<1024, 512, 0, stream>>>(H, Wt, bias, out, ws);
}

// Round 17
// 210.496 us; speedup vs baseline: 1.0287x; 1.0287x over previous
//
#include <hip/hip_runtime.h>
#include <math.h>

// Problem constants
#define T_TOKENS 32768
#define DIM      2048
#define NEXP     256
#define NGROUP   8
#define GSIZE    32
#define TOPG     4
#define TOPK     8
#define SCALE    2.5
#define TAU      1e-5f     // rescue margin; >=20x RMS of 3-term bf16-split err

// Main-pass tiling
#define BM  64
#define NIT 32             // iterations of 64-k (2 sub-steps of 32)
#define SC_STRIDE 257

#define RLIST_OFF 16                 // ints; ws[0] = counter
#define WPACK_OFF_BYTES (1 << 18)    // 256 KiB into d_ws

typedef __attribute__((ext_vector_type(8))) short bf16x8;
typedef __attribute__((ext_vector_type(8))) unsigned short u16x8;
typedef __attribute__((ext_vector_type(4))) float f32x4;

__device__ __forceinline__ unsigned short f2bf_rne(float f) {
    unsigned u = __float_as_uint(f);
    u += 0x7fffu + ((u >> 16) & 1u);
    return (unsigned short)(u >> 16);
}
__device__ __forceinline__ float bf2f(unsigned short h) {
    return __uint_as_float(((unsigned)h) << 16);
}

// LDS-only barrier: orders ds ops across the workgroup but leaves global
// (vmcnt) loads in flight.
__device__ __forceinline__ void lds_barrier() {
    __builtin_amdgcn_sched_barrier(0);
    asm volatile("s_waitcnt lgkmcnt(0)" ::: "memory");
    __builtin_amdgcn_s_barrier();
    __builtin_amdgcn_sched_barrier(0);
}

// ------------------------------------------------------------- pack W ----
// Wpack slot (s, n, h, lane) holds 8 bf16: W[e=16n+(lane&15)][k=32s+(lane>>4)*8+i]
__global__ void pack_w_kernel(const float* __restrict__ Wt,
                              unsigned short* __restrict__ wp,
                              int* __restrict__ ws) {
    if (blockIdx.x == 0 && threadIdx.x == 0) ws[0] = 0;   // rescue counter
    const int slot = blockIdx.x * 256 + threadIdx.x;      // 0..65535
    const int lane = slot & 63;
    const int n    = (slot >> 6) & 15;
    const int s    = slot >> 10;
    const int e    = n * 16 + (lane & 15);
    const int k0   = s * 32 + (lane >> 4) * 8;
    const float* src = Wt + (size_t)e * DIM + k0;
    const float4 v0 = *(const float4*)src;
    const float4 v1 = *(const float4*)(src + 4);
    const float a[8] = {v0.x, v0.y, v0.z, v0.w, v1.x, v1.y, v1.z, v1.w};
    union { unsigned short u[8]; u16x8 v; } uh, ul;
    #pragma unroll
    for (int i = 0; i < 8; ++i) {
        const unsigned short hb = f2bf_rne(a[i]);
        uh.u[i] = hb;
        ul.u[i] = f2bf_rne(a[i] - bf2f(hb));
    }
    const size_t base = ((size_t)(s * 16 + n) * 2) * 64 + lane;
    *(u16x8*)(wp + base * 8)        = uh.v;   // hi
    *(u16x8*)(wp + (base + 64) * 8) = ul.v;   // lo
}

// ---------------------------------------------------------------- main ----
// EXACT round-15 kernel (proven: 169 us rocprof, bank-conflict-free, no spill).
__global__ __launch_bounds__(512, 4) void router_main(
    const float* __restrict__ H,
    const float* __restrict__ bias,
    const unsigned short* __restrict__ wp,
    float* __restrict__ out,
    int* __restrict__ ws)
{
    __shared__ __align__(16) char smraw[BM * SC_STRIDE * 4];
    __shared__ float biasS[NEXP];

    typedef unsigned short AhlBuf[2][2][4][64][8];   // [sub][h][m][slot][i]
    AhlBuf* Ahl = reinterpret_cast<AhlBuf*>(smraw);  // Ahl[buf]
    float*  Sc  = reinterpret_cast<float*>(smraw);

    const int tid  = threadIdx.x;
    const int lane = tid & 63;
    const int w    = tid >> 6;           // wave 0..7
    const int t0   = blockIdx.x * BM;

    if (tid < NEXP) biasS[tid] = bias[tid];

    f32x4 acc[4][2];   // [m][jj], expert tile = 2w+jj
    #pragma unroll
    for (int m = 0; m < 4; ++m)
        #pragma unroll
        for (int jj = 0; jj < 2; ++jj)
            acc[m][jj] = (f32x4){0.f, 0.f, 0.f, 0.f};

    const int arow = tid >> 3;           // 0..63
    const int koct = tid & 7;            // 0..7
    const int sub  = koct >> 2;
    const int kq   = koct & 3;
    const int am   = arow >> 4;
    // bank-quad XOR swizzle (r15-verified, 50x conflict reduction)
    const int lw   = (kq << 4) | (((arow & 15) ^ (kq << 1) ^ sub) & 15);
    const float* Aptr = H + (size_t)(t0 + arow) * DIM + koct * 8;

    auto loadH = [&](int it, float4& x0, float4& x1) {
        const float* p = Aptr + (size_t)it * 64;
        x0 = *(const float4*)p;
        x1 = *(const float4*)(p + 4);
    };
    auto stageIter = [&](int b, const float4& x0, const float4& x1) {
        const float a[8] = {x0.x, x0.y, x0.z, x0.w, x1.x, x1.y, x1.z, x1.w};
        union { unsigned short u[8]; u16x8 v; } uh, ul;
        #pragma unroll
        for (int i = 0; i < 8; ++i) {
            const unsigned short hb = f2bf_rne(a[i]);
            uh.u[i] = hb;
            ul.u[i] = f2bf_rne(a[i] - bf2f(hb));
        }
        *(u16x8*)&Ahl[b][sub][0][am][lw][0] = uh.v;
        *(u16x8*)&Ahl[b][sub][1][am][lw][0] = ul.v;
    };
    auto loadB = [&](int s, bf16x8 (&Bh)[2], bf16x8 (&Bl)[2]) {
        #pragma unroll
        for (int jj = 0; jj < 2; ++jj) {
            const size_t slot = ((size_t)(s * 16 + 2 * w + jj) * 2) * 64 + lane;
            Bh[jj] = *(const bf16x8*)(wp + slot * 8);
            Bl[jj] = *(const bf16x8*)(wp + (slot + 64) * 8);
        }
    };
    auto computeSub = [&](int b, int ss, bf16x8 (&Bh)[2], bf16x8 (&Bl)[2]) {
        const int rslot = (lane & 48) | (((lane & 15) ^ ((lane >> 4) << 1) ^ ss) & 15);
        bf16x8 Ah[4], Al[4];
        #pragma unroll
        for (int m = 0; m < 4; ++m) {
            Ah[m] = *(const bf16x8*)&Ahl[b][ss][0][m][rslot][0];
            Al[m] = *(const bf16x8*)&Ahl[b][ss][1][m][rslot][0];
        }
        __builtin_amdgcn_s_setprio(1);
        #pragma unroll
        for (int m = 0; m < 4; ++m)
            #pragma unroll
            for (int jj = 0; jj < 2; ++jj) {
                acc[m][jj] = __builtin_amdgcn_mfma_f32_16x16x32_bf16(Al[m], Bh[jj], acc[m][jj], 0, 0, 0);
                acc[m][jj] = __builtin_amdgcn_mfma_f32_16x16x32_bf16(Ah[m], Bl[jj], acc[m][jj], 0, 0, 0);
                acc[m][jj] = __builtin_amdgcn_mfma_f32_16x16x32_bf16(Ah[m], Bh[jj], acc[m][jj], 0, 0, 0);
            }
        __builtin_amdgcn_s_setprio(0);
    };

    bf16x8 Ba_h[2], Ba_l[2], Bb_h[2], Bb_l[2];
    float4 hS0, hS1, hL0, hL1;

    {
        float4 c0, c1;
        loadH(0, c0, c1);
        stageIter(0, c0, c1);
    }
    loadH(1, hS0, hS1);
    loadB(0, Ba_h, Ba_l);
    lds_barrier();

    for (int it = 0; it < NIT; it += 2) {
        loadH(min(it + 2, NIT - 1), hL0, hL1);
        stageIter(1, hS0, hS1);
        loadB(2 * it + 1, Bb_h, Bb_l);
        computeSub(0, 0, Ba_h, Ba_l);
        loadB(min(2 * it + 2, 2 * NIT - 1), Ba_h, Ba_l);
        computeSub(0, 1, Bb_h, Bb_l);
        lds_barrier();

        loadH(min(it + 3, NIT - 1), hS0, hS1);
        if (it + 2 < NIT) stageIter(0, hL0, hL1);
        loadB(min(2 * it + 3, 2 * NIT - 1), Bb_h, Bb_l);
        computeSub(1, 0, Ba_h, Ba_l);
        loadB(min(2 * it + 4, 2 * NIT - 1), Ba_h, Ba_l);
        computeSub(1, 1, Bb_h, Bb_l);
        lds_barrier();
    }

    // ---- epilogue: biased sigmoid -> Sc ----
    const int rbase = (lane >> 4) * 4;
    const int cc    = lane & 15;
    #pragma unroll
    for (int m = 0; m < 4; ++m)
        #pragma unroll
        for (int jj = 0; jj < 2; ++jj)
            #pragma unroll
            for (int r = 0; r < 4; ++r) {
                const int token  = 16 * m + rbase + r;
                const int expert = 16 * (2 * w + jj) + cc;
                const float sg = 1.0f / (1.0f + expf(-acc[m][jj][r]));
                Sc[token * SC_STRIDE + expert] = sg + biasS[expert];
            }
    __syncthreads();

    // ---- routing (fp32) + margin check (round-4..15 proven) ----
    if (tid < BM) {
        float* row = &Sc[tid * SC_STRIDE];

        float gs[NGROUP];
        for (int g = 0; g < NGROUP; ++g) {
            const int base = g * GSIZE;
            float m1 = -3e38f, m2 = -3e38f;
            for (int j = 0; j < GSIZE; ++j) {
                const float v = row[base + j];
                if (v > m1) { m2 = m1; m1 = v; }
                else if (v > m2) { m2 = v; }
            }
            gs[g] = m1 + m2;
        }

        unsigned gsel = 0;
        float minSel = 3e38f, maxUn = -3e38f;
        #pragma unroll
        for (int g = 0; g < NGROUP; ++g) {
            int rank = 0;
            #pragma unroll
            for (int h = 0; h < NGROUP; ++h)
                rank += (gs[h] > gs[g]) || (gs[h] == gs[g] && h < g);
            if (rank < TOPG) { gsel |= 1u << g; minSel = fminf(minSel, gs[g]); }
            else             { maxUn = fmaxf(maxUn, gs[g]); }
        }
        float minMargin = minSel - maxUn;

        float wk[TOPK];
        int   ik[TOPK];
        float wsum = 0.0f;
        float prev = 3e38f;
        #pragma unroll
        for (int k = 0; k < TOPK + 1; ++k) {
            float bv = -3e38f;
            int   bi = 0;
            for (int g = 0; g < NGROUP; ++g) {
                if (!((gsel >> g) & 1u)) continue;
                const int base = g * GSIZE;
                for (int j = 0; j < GSIZE; ++j) {
                    const int e = base + j;
                    const float v = row[e];
                    if (v > bv) { bv = v; bi = e; }
                }
            }
            if (k > 0) minMargin = fminf(minMargin, prev - bv);
            prev = bv;
            if (k < TOPK) {
                const float wv = bv - biasS[bi];
                wk[k] = wv; ik[k] = bi; wsum += wv;
                row[bi] = -3e38f;
            }
        }

        const float norm = (float)SCALE / wsum;
        const size_t t = (size_t)(t0 + tid);
        float* oi = out + t * TOPK;
        float* ow = out + (size_t)T_TOKENS * TOPK + t * TOPK;
        #pragma unroll
        for (int k = 0; k < TOPK; ++k) {
            oi[k] = (float)ik[k];
            ow[k] = wk[k] * norm;
        }

        if (minMargin < TAU) {
            const int r = atomicAdd(ws, 1);
            ws[RLIST_OFF + r] = t0 + tid;
        }
    }
}

// -------------------------------------------------------------- rescue ----
// BATCHED: 4 tokens per block-iteration -> each W float4 feeds 4 tokens' fp64
// FMAs (W re-read traffic /4, under the L2 ceiling). 512 threads = 256
// experts x 2 k-halves. Routing: wave w handles token w (r14-verified shfl).
#define RB 4
__global__ __launch_bounds__(512) void router_rescue(
    const float* __restrict__ H,
    const float* __restrict__ Wt,
    const float* __restrict__ bias,
    float* __restrict__ out,
    const int* __restrict__ ws)
{
    __shared__ float  Hs[RB][DIM];         // 32 KiB
    __shared__ double PartD[2][RB][NEXP];  // 16 KiB
    __shared__ double Sd[RB][NEXP];        //  8 KiB
    __shared__ double biasD[NEXP];         //  2 KiB

    const int tid  = threadIdx.x;
    const int lane = tid & 63;
    const int wv_  = tid >> 6;          // wave 0..7
    const int nR   = ws[0];
    const int re   = tid & 255;         // expert
    const int kh   = tid >> 8;          // k-half 0/1

    if (tid < NEXP) biasD[tid] = (double)bias[tid];

    for (int base = blockIdx.x * RB; base < nR; base += gridDim.x * RB) {
        const int nt = min(RB, nR - base);
        __syncthreads();   // prev iteration's readers done; biasD ready

        // stage nt H rows (fp32): 512 threads x 1 float4 per row
        for (int j = 0; j < nt; ++j) {
            const size_t t = (size_t)ws[RLIST_OFF + base + j];
            *(float4*)&Hs[j][tid * 4] = *(const float4*)&H[t * DIM + tid * 4];
        }
        __syncthreads();

        // fp64 dot: thread = (expert, k-half); one chain per token (4-way ILP);
        // W float4 loaded once, used for all RB tokens. Missing tokens compute
        // garbage (stale LDS) and are discarded by the nt guards below.
        {
            const float* wr = Wt + (size_t)re * DIM + kh * 1024;
            const float* h0 = &Hs[0][kh * 1024];
            const float* h1 = &Hs[1][kh * 1024];
            const float* h2 = &Hs[2][kh * 1024];
            const float* h3 = &Hs[3][kh * 1024];
            double a0 = 0.0, a1 = 0.0, a2 = 0.0, a3 = 0.0;
            #pragma unroll 2
            for (int k = 0; k < 1024; k += 4) {
                const float4 wf = *(const float4*)(wr + k);
                const double w0 = (double)wf.x, w1 = (double)wf.y;
                const double w2 = (double)wf.z, w3 = (double)wf.w;
                const float4 x0 = *(const float4*)(h0 + k);
                const float4 x1 = *(const float4*)(h1 + k);
                const float4 x2 = *(const float4*)(h2 + k);
                const float4 x3 = *(const float4*)(h3 + k);
                a0 = fma((double)x0.x, w0, a0); a1 = fma((double)x1.x, w0, a1);
                a2 = fma((double)x2.x, w0, a2); a3 = fma((double)x3.x, w0, a3);
                a0 = fma((double)x0.y, w1, a0); a1 = fma((double)x1.y, w1, a1);
                a2 = fma((double)x2.y, w1, a2); a3 = fma((double)x3.y, w1, a3);
                a0 = fma((double)x0.z, w2, a0); a1 = fma((double)x1.z, w2, a1);
                a2 = fma((double)x2.z, w2, a2); a3 = fma((double)x3.z, w2, a3);
                a0 = fma((double)x0.w, w3, a0); a1 = fma((double)x1.w, w3, a1);
                a2 = fma((double)x2.w, w3, a2); a3 = fma((double)x3.w, w3, a3);
            }
            PartD[kh][0][re] = a0;
            PartD[kh][1][re] = a1;
            PartD[kh][2][re] = a2;
            PartD[kh][3][re] = a3;
        }
        __syncthreads();

        if (tid < NEXP) {
            #pragma unroll
            for (int j = 0; j < RB; ++j) {
                const double sum = PartD[0][j][tid] + PartD[1][j][tid];
                Sd[j][tid] = 1.0 / (1.0 + exp(-sum)) + biasD[tid];
            }
        }
        __syncthreads();

        // ---- wave-parallel fp64 routing: wave w = token w (r14-verified) ----
        if (wv_ < nt) {
            const int e0 = lane * 4;
            const int gm = lane >> 3;
            const size_t t = (size_t)ws[RLIST_OFF + base + wv_];

            double sv[4];
            #pragma unroll
            for (int j = 0; j < 4; ++j) sv[j] = Sd[wv_][e0 + j];

            double m1 = sv[0], m2 = -1e300;
            #pragma unroll
            for (int j = 1; j < 4; ++j) {
                if (sv[j] > m1) { m2 = m1; m1 = sv[j]; }
                else if (sv[j] > m2) { m2 = sv[j]; }
            }
            #pragma unroll
            for (int mask = 1; mask <= 4; mask <<= 1) {
                const double o1 = __shfl_xor(m1, mask);
                const double o2 = __shfl_xor(m2, mask);
                const double lo = fmin(m1, o1);
                m1 = fmax(m1, o1);
                m2 = fmax(lo, fmax(m2, o2));
            }
            const double gsm = m1 + m2;

            double gsd[NGROUP];
            #pragma unroll
            for (int g = 0; g < NGROUP; ++g) gsd[g] = __shfl(gsm, g * 8);

            unsigned gsel = 0;
            #pragma unroll
            for (int g = 0; g < NGROUP; ++g) {
                int rank = 0;
                #pragma unroll
                for (int h = 0; h < NGROUP; ++h)
                    rank += (gsd[h] > gsd[g]) || (gsd[h] == gsd[g] && h < g);
                if (rank < TOPG) gsel |= 1u << g;
            }
            const bool allowed = (gsel >> gm) & 1u;

            double wkd[TOPK];
            int    ikd[TOPK];
            double wsum = 0.0;
            #pragma unroll
            for (int k = 0; k < TOPK; ++k) {
                double bv = -1e300;
                int    be = 1 << 30;
                if (allowed) {
                    #pragma unroll
                    for (int j = 0; j < 4; ++j)
                        if (sv[j] > bv) { bv = sv[j]; be = e0 + j; }
                }
                #pragma unroll
                for (int mask = 1; mask <= 32; mask <<= 1) {
                    const double ov = __shfl_xor(bv, mask);
                    const int    oe = __shfl_xor(be, mask);
                    if (ov > bv || (ov == bv && oe < be)) { bv = ov; be = oe; }
                }
                const double wvv = bv - biasD[be];
                wkd[k] = wvv; ikd[k] = be; wsum += wvv;
                const bool own = ((be >> 2) == lane);
                #pragma unroll
                for (int j = 0; j < 4; ++j)
                    if (own && (be & 3) == j) sv[j] = -1e300;
            }

            if (lane == 0) {
                const double norm = SCALE / wsum;
                float* oi = out + t * TOPK;
                float* ow = out + (size_t)T_TOKENS * TOPK + t * TOPK;
                #pragma unroll
                for (int k = 0; k < TOPK; ++k) {
                    oi[k] = (float)ikd[k];
                    ow[k] = (float)(wkd[k] * norm);
                }
            }
        }
    }
}

extern "C" void kernel_launch(void* const* d_in, const int* in_sizes, int n_in,
                              void* d_out, int out_size, void* d_ws, size_t ws_size,
                              hipStream_t stream) {
    const float* H    = (const float*)d_in[0];
    const float* Wt   = (const float*)d_in[1];
    const float* bias = (const float*)d_in[2];
    float* out = (float*)d_out;
    int*   ws  = (int*)d_ws;
    unsigned short* wp = (unsigned short*)((char*)d_ws + WPACK_OFF_BYTES);

    pack_w_kernel<<<256, 256, 0, stream>>>(Wt, wp, ws);
    router_main<<<T_TOKENS / BM, 512, 0, stream>>>(H, bias, wp, out, ws);
    router_rescue<<<256, 512, 0, stream>>>(H, Wt, bias, out, ws);
}

// Round 18
// 202.807 us; speedup vs baseline: 1.0677x; 1.0379x over previous
//
#include <hip/hip_runtime.h>
#include <math.h>

// Problem constants
#define T_TOKENS 32768
#define DIM      2048
#define NEXP     256
#define NGROUP   8
#define GSIZE    32
#define TOPG     4
#define TOPK     8
#define SCALE    2.5
#define TAU      1e-5f     // rescue margin; >=25x RMS of 3-term bf16-split err

// Main-pass tiling
#define BM  64
#define NIT 32             // iterations of 64-k (2 sub-steps of 32)
#define SC_STRIDE 257

#define RLIST_OFF 16                 // ints; ws[0] = counter
#define WPACK_OFF_BYTES (1 << 18)    // 256 KiB into d_ws

typedef __attribute__((ext_vector_type(8))) short bf16x8;
typedef __attribute__((ext_vector_type(8))) unsigned short u16x8;
typedef __attribute__((ext_vector_type(4))) float f32x4;

__device__ __forceinline__ unsigned short f2bf_rne(float f) {
    unsigned u = __float_as_uint(f);
    u += 0x7fffu + ((u >> 16) & 1u);
    return (unsigned short)(u >> 16);
}
__device__ __forceinline__ float bf2f(unsigned short h) {
    return __uint_as_float(((unsigned)h) << 16);
}

// LDS-only barrier: orders ds ops across the workgroup but leaves global
// (vmcnt) loads in flight — __syncthreads would drain vmcnt(0) and expose
// the H/B prefetch latency every iteration (m97 stall).
__device__ __forceinline__ void lds_barrier() {
    __builtin_amdgcn_sched_barrier(0);
    asm volatile("s_waitcnt lgkmcnt(0)" ::: "memory");
    __builtin_amdgcn_s_barrier();
    __builtin_amdgcn_sched_barrier(0);
}

// ------------------------------------------------------------- pack W ----
// Wpack slot (s, n, h, lane) holds 8 bf16: W[e=16n+(lane&15)][k=32s+(lane>>4)*8+i]
__global__ void pack_w_kernel(const float* __restrict__ Wt,
                              unsigned short* __restrict__ wp,
                              int* __restrict__ ws) {
    if (blockIdx.x == 0 && threadIdx.x == 0) ws[0] = 0;   // rescue counter
    const int slot = blockIdx.x * 256 + threadIdx.x;      // 0..65535
    const int lane = slot & 63;
    const int n    = (slot >> 6) & 15;
    const int s    = slot >> 10;
    const int e    = n * 16 + (lane & 15);
    const int k0   = s * 32 + (lane >> 4) * 8;
    const float* src = Wt + (size_t)e * DIM + k0;
    const float4 v0 = *(const float4*)src;
    const float4 v1 = *(const float4*)(src + 4);
    const float a[8] = {v0.x, v0.y, v0.z, v0.w, v1.x, v1.y, v1.z, v1.w};
    union { unsigned short u[8]; u16x8 v; } uh, ul;
    #pragma unroll
    for (int i = 0; i < 8; ++i) {
        const unsigned short hb = f2bf_rne(a[i]);
        uh.u[i] = hb;
        ul.u[i] = f2bf_rne(a[i] - bf2f(hb));
    }
    const size_t base = ((size_t)(s * 16 + n) * 2) * 64 + lane;
    *(u16x8*)(wp + base * 8)        = uh.v;   // hi
    *(u16x8*)(wp + (base + 64) * 8) = ul.v;   // lo
}

// ---------------------------------------------------------------- main ----
// Round-11 kernel + bank-quad XOR swizzle on the A-stage LDS slots (r15,
// proven 169 us rocprof / 203 us total). Swizzle: slot = (kq<<4) |
// (r15 ^ (kq<<1) ^ sub); writers hit all 8 bank quads, reads stay a bijection.
__global__ __launch_bounds__(512, 4) void router_main(
    const float* __restrict__ H,
    const float* __restrict__ bias,
    const unsigned short* __restrict__ wp,
    float* __restrict__ out,
    int* __restrict__ ws)
{
    __shared__ __align__(16) char smraw[BM * SC_STRIDE * 4];
    __shared__ float biasS[NEXP];

    typedef unsigned short AhlBuf[2][2][4][64][8];   // [sub][h][m][slot][i]
    AhlBuf* Ahl = reinterpret_cast<AhlBuf*>(smraw);  // Ahl[buf]
    float*  Sc  = reinterpret_cast<float*>(smraw);

    const int tid  = threadIdx.x;
    const int lane = tid & 63;
    const int w    = tid >> 6;           // wave 0..7
    const int t0   = blockIdx.x * BM;

    if (tid < NEXP) biasS[tid] = bias[tid];

    f32x4 acc[4][2];   // [m][jj], expert tile = 2w+jj
    #pragma unroll
    for (int m = 0; m < 4; ++m)
        #pragma unroll
        for (int jj = 0; jj < 2; ++jj)
            acc[m][jj] = (f32x4){0.f, 0.f, 0.f, 0.f};

    const int arow = tid >> 3;           // 0..63
    const int koct = tid & 7;            // 0..7
    const int sub  = koct >> 2;
    const int kq   = koct & 3;
    const int am   = arow >> 4;
    // swizzled write slot: spreads the 8 same-r15 lanes over all 8 bank quads
    const int lw   = (kq << 4) | (((arow & 15) ^ (kq << 1) ^ sub) & 15);
    const float* Aptr = H + (size_t)(t0 + arow) * DIM + koct * 8;

    auto loadH = [&](int it, float4& x0, float4& x1) {
        const float* p = Aptr + (size_t)it * 64;
        x0 = *(const float4*)p;
        x1 = *(const float4*)(p + 4);
    };
    auto stageIter = [&](int b, const float4& x0, const float4& x1) {
        const float a[8] = {x0.x, x0.y, x0.z, x0.w, x1.x, x1.y, x1.z, x1.w};
        union { unsigned short u[8]; u16x8 v; } uh, ul;
        #pragma unroll
        for (int i = 0; i < 8; ++i) {
            const unsigned short hb = f2bf_rne(a[i]);
            uh.u[i] = hb;
            ul.u[i] = f2bf_rne(a[i] - bf2f(hb));
        }
        *(u16x8*)&Ahl[b][sub][0][am][lw][0] = uh.v;
        *(u16x8*)&Ahl[b][sub][1][am][lw][0] = ul.v;
    };
    auto loadB = [&](int s, bf16x8 (&Bh)[2], bf16x8 (&Bl)[2]) {
        #pragma unroll
        for (int jj = 0; jj < 2; ++jj) {
            const size_t slot = ((size_t)(s * 16 + 2 * w + jj) * 2) * 64 + lane;
            Bh[jj] = *(const bf16x8*)(wp + slot * 8);
            Bl[jj] = *(const bf16x8*)(wp + (slot + 64) * 8);
        }
    };
    auto computeSub = [&](int b, int ss, bf16x8 (&Bh)[2], bf16x8 (&Bl)[2]) {
        // inverse swizzle at read: ss is compile-time per call site
        const int rslot = (lane & 48) | (((lane & 15) ^ ((lane >> 4) << 1) ^ ss) & 15);
        bf16x8 Ah[4], Al[4];
        #pragma unroll
        for (int m = 0; m < 4; ++m) {
            Ah[m] = *(const bf16x8*)&Ahl[b][ss][0][m][rslot][0];
            Al[m] = *(const bf16x8*)&Ahl[b][ss][1][m][rslot][0];
        }
        __builtin_amdgcn_s_setprio(1);
        #pragma unroll
        for (int m = 0; m < 4; ++m)
            #pragma unroll
            for (int jj = 0; jj < 2; ++jj) {
                acc[m][jj] = __builtin_amdgcn_mfma_f32_16x16x32_bf16(Al[m], Bh[jj], acc[m][jj], 0, 0, 0);
                acc[m][jj] = __builtin_amdgcn_mfma_f32_16x16x32_bf16(Ah[m], Bl[jj], acc[m][jj], 0, 0, 0);
                acc[m][jj] = __builtin_amdgcn_mfma_f32_16x16x32_bf16(Ah[m], Bh[jj], acc[m][jj], 0, 0, 0);
            }
        __builtin_amdgcn_s_setprio(0);
    };

    bf16x8 Ba_h[2], Ba_l[2], Bb_h[2], Bb_l[2];
    float4 hS0, hS1, hL0, hL1;

    {
        float4 c0, c1;
        loadH(0, c0, c1);
        stageIter(0, c0, c1);
    }
    loadH(1, hS0, hS1);
    loadB(0, Ba_h, Ba_l);
    lds_barrier();

    for (int it = 0; it < NIT; it += 2) {
        loadH(min(it + 2, NIT - 1), hL0, hL1);
        stageIter(1, hS0, hS1);
        loadB(2 * it + 1, Bb_h, Bb_l);
        computeSub(0, 0, Ba_h, Ba_l);
        loadB(min(2 * it + 2, 2 * NIT - 1), Ba_h, Ba_l);
        computeSub(0, 1, Bb_h, Bb_l);
        lds_barrier();

        loadH(min(it + 3, NIT - 1), hS0, hS1);
        if (it + 2 < NIT) stageIter(0, hL0, hL1);
        loadB(min(2 * it + 3, 2 * NIT - 1), Bb_h, Bb_l);
        computeSub(1, 0, Ba_h, Ba_l);
        loadB(min(2 * it + 4, 2 * NIT - 1), Ba_h, Ba_l);
        computeSub(1, 1, Bb_h, Bb_l);
        lds_barrier();
    }

    // ---- epilogue: biased sigmoid -> Sc ----
    const int rbase = (lane >> 4) * 4;
    const int cc    = lane & 15;
    #pragma unroll
    for (int m = 0; m < 4; ++m)
        #pragma unroll
        for (int jj = 0; jj < 2; ++jj)
            #pragma unroll
            for (int r = 0; r < 4; ++r) {
                const int token  = 16 * m + rbase + r;
                const int expert = 16 * (2 * w + jj) + cc;
                const float sg = 1.0f / (1.0f + expf(-acc[m][jj][r]));
                Sc[token * SC_STRIDE + expert] = sg + biasS[expert];
            }
    __syncthreads();

    // ---- routing (fp32) + margin check (round-4..15 proven) ----
    if (tid < BM) {
        float* row = &Sc[tid * SC_STRIDE];

        float gs[NGROUP];
        for (int g = 0; g < NGROUP; ++g) {
            const int base = g * GSIZE;
            float m1 = -3e38f, m2 = -3e38f;
            for (int j = 0; j < GSIZE; ++j) {
                const float v = row[base + j];
                if (v > m1) { m2 = m1; m1 = v; }
                else if (v > m2) { m2 = v; }
            }
            gs[g] = m1 + m2;
        }

        unsigned gsel = 0;
        float minSel = 3e38f, maxUn = -3e38f;
        #pragma unroll
        for (int g = 0; g < NGROUP; ++g) {
            int rank = 0;
            #pragma unroll
            for (int h = 0; h < NGROUP; ++h)
                rank += (gs[h] > gs[g]) || (gs[h] == gs[g] && h < g);
            if (rank < TOPG) { gsel |= 1u << g; minSel = fminf(minSel, gs[g]); }
            else             { maxUn = fmaxf(maxUn, gs[g]); }
        }
        float minMargin = minSel - maxUn;

        float wk[TOPK];
        int   ik[TOPK];
        float wsum = 0.0f;
        float prev = 3e38f;
        #pragma unroll
        for (int k = 0; k < TOPK + 1; ++k) {
            float bv = -3e38f;
            int   bi = 0;
            for (int g = 0; g < NGROUP; ++g) {
                if (!((gsel >> g) & 1u)) continue;
                const int base = g * GSIZE;
                for (int j = 0; j < GSIZE; ++j) {
                    const int e = base + j;
                    const float v = row[e];
                    if (v > bv) { bv = v; bi = e; }
                }
            }
            if (k > 0) minMargin = fminf(minMargin, prev - bv);
            prev = bv;
            if (k < TOPK) {
                const float wv = bv - biasS[bi];
                wk[k] = wv; ik[k] = bi; wsum += wv;
                row[bi] = -3e38f;
            }
        }

        const float norm = (float)SCALE / wsum;
        const size_t t = (size_t)(t0 + tid);
        float* oi = out + t * TOPK;
        float* ow = out + (size_t)T_TOKENS * TOPK + t * TOPK;
        #pragma unroll
        for (int k = 0; k < TOPK; ++k) {
            oi[k] = (float)ik[k];
            ow[k] = wk[k] * norm;
        }

        if (minMargin < TAU) {
            const int r = atomicAdd(ws, 1);
            ws[RLIST_OFF + r] = t0 + tid;
        }
    }
}

// -------------------------------------------------------------- rescue ----
// 1 token per block-iteration; 512 threads = 256 experts x 2 k-halves for the
// fp64 dot; routing is wave-parallel (r3-verified shfl logic). Grid 1024 so
// all ~300 flagged tokens resolve concurrently (latency-, not BW-, limited).
__global__ __launch_bounds__(512) void router_rescue(
    const float* __restrict__ H,
    const float* __restrict__ Wt,
    const float* __restrict__ bias,
    float* __restrict__ out,
    const int* __restrict__ ws)
{
    __shared__ float  Hrow[DIM];        // 8 KiB
    __shared__ double PartD[2][NEXP];   // 4 KiB
    __shared__ double Sd[NEXP];         // 2 KiB
    __shared__ double biasD[NEXP];      // 2 KiB

    const int tid = threadIdx.x;
    const int nR  = ws[0];
    const int re  = tid & 255;          // expert
    const int kh  = tid >> 8;           // k-half 0/1

    if (tid < NEXP) biasD[tid] = (double)bias[tid];

    for (int idx = blockIdx.x; idx < nR; idx += gridDim.x) {
        const size_t t = (size_t)ws[RLIST_OFF + idx];
        __syncthreads();   // previous iteration's readers done (and biasD ready)

        *(float4*)&Hrow[tid * 4] = *(const float4*)&H[t * DIM + tid * 4];
        __syncthreads();

        {
            const float* wr = Wt + (size_t)re * DIM + kh * 1024;
            const float* hr = Hrow + kh * 1024;
            double c0 = 0.0, c1 = 0.0, c2 = 0.0, c3 = 0.0;
            #pragma unroll 4
            for (int k = 0; k < 1024; k += 4) {
                const float4 wv = *(const float4*)(wr + k);
                c0 = fma((double)hr[k + 0], (double)wv.x, c0);
                c1 = fma((double)hr[k + 1], (double)wv.y, c1);
                c2 = fma((double)hr[k + 2], (double)wv.z, c2);
                c3 = fma((double)hr[k + 3], (double)wv.w, c3);
            }
            PartD[kh][re] = ((c0 + c1) + c2) + c3;
        }
        __syncthreads();

        if (tid < NEXP) {
            const double sum = PartD[0][tid] + PartD[1][tid];
            Sd[tid] = 1.0 / (1.0 + exp(-sum)) + biasD[tid];
        }
        __syncthreads();

        if (tid < 64) {
            const int lane = tid;
            const int e0   = lane * 4;
            const int gm   = lane >> 3;

            double sv[4];
            #pragma unroll
            for (int j = 0; j < 4; ++j) sv[j] = Sd[e0 + j];

            double m1 = sv[0], m2 = -1e300;
            #pragma unroll
            for (int j = 1; j < 4; ++j) {
                if (sv[j] > m1) { m2 = m1; m1 = sv[j]; }
                else if (sv[j] > m2) { m2 = sv[j]; }
            }
            #pragma unroll
            for (int mask = 1; mask <= 4; mask <<= 1) {
                const double o1 = __shfl_xor(m1, mask);
                const double o2 = __shfl_xor(m2, mask);
                const double lo = fmin(m1, o1);
                m1 = fmax(m1, o1);
                m2 = fmax(lo, fmax(m2, o2));
            }
            const double gsm = m1 + m2;

            double gsd[NGROUP];
            #pragma unroll
            for (int g = 0; g < NGROUP; ++g) gsd[g] = __shfl(gsm, g * 8);

            unsigned gsel = 0;
            #pragma unroll
            for (int g = 0; g < NGROUP; ++g) {
                int rank = 0;
                #pragma unroll
                for (int h = 0; h < NGROUP; ++h)
                    rank += (gsd[h] > gsd[g]) || (gsd[h] == gsd[g] && h < g);
                if (rank < TOPG) gsel |= 1u << g;
            }
            const bool allowed = (gsel >> gm) & 1u;

            double wkd[TOPK];
            int    ikd[TOPK];
            double wsum = 0.0;
            #pragma unroll
            for (int k = 0; k < TOPK; ++k) {
                double bv = -1e300;
                int    be = 1 << 30;
                if (allowed) {
                    #pragma unroll
                    for (int j = 0; j < 4; ++j)
                        if (sv[j] > bv) { bv = sv[j]; be = e0 + j; }
                }
                #pragma unroll
                for (int mask = 1; mask <= 32; mask <<= 1) {
                    const double ov = __shfl_xor(bv, mask);
                    const int    oe = __shfl_xor(be, mask);
                    if (ov > bv || (ov == bv && oe < be)) { bv = ov; be = oe; }
                }
                const double wv = bv - biasD[be];
                wkd[k] = wv; ikd[k] = be; wsum += wv;
                const bool own = ((be >> 2) == lane);
                #pragma unroll
                for (int j = 0; j < 4; ++j)
                    if (own && (be & 3) == j) sv[j] = -1e300;
            }

            if (lane == 0) {
                const double norm = SCALE / wsum;
                float* oi = out + t * TOPK;
                float* ow = out + (size_t)T_TOKENS * TOPK + t * TOPK;
                #pragma unroll
                for (int k = 0; k < TOPK; ++k) {
                    oi[k] = (float)ikd[k];
                    ow[k] = (float)(wkd[k] * norm);
                }
            }
        }
    }
}

extern "C" void kernel_launch(void* const* d_in, const int* in_sizes, int n_in,
                              void* d_out, int out_size, void* d_ws, size_t ws_size,
                              hipStream_t stream) {
    const float* H    = (const float*)d_in[0];
    const float* Wt   = (const float*)d_in[1];
    const float* bias = (const float*)d_in[2];
    float* out = (float*)d_out;
    int*   ws  = (int*)d_ws;
    unsigned short* wp = (unsigned short*)((char*)d_ws + WPACK_OFF_BYTES);

    pack_w_kernel<<<256, 256, 0, stream>>>(Wt, wp, ws);
    router_main<<<T_TOKENS / BM, 512, 0, stream>>>(H, bias, wp, out, ws);
    router_rescue<<<1024, 512, 0, stream>>>(H, Wt, bias, out, ws);
}